// Round 1
// baseline (755.405 us; speedup 1.0000x reference)
//
#include <hip/hip_runtime.h>
#include <math.h>

#define BB 8
#define NN 50000
#define FF 256
#define KK 1024

// ---------- helpers ----------
__device__ __forceinline__ unsigned long long key64(double x) {
    unsigned long long u = (unsigned long long)__double_as_longlong(x);
    // monotone map: flip all bits if negative, else flip sign bit
    u ^= (u & 0x8000000000000000ull) ? 0xFFFFFFFFFFFFFFFFull : 0x8000000000000000ull;
    return u;
}

// ---------- phase 1: scores[b*N+n] = dot(emb[b,n,:], scorer)/||scorer|| + mask ----------
// One wave per row; lane i handles float4 at f = 4*i (contiguous 1KB per wave-load).
__global__ __launch_bounds__(256) void score_kernel(const float* __restrict__ emb,
                                                    const float* __restrict__ mask,
                                                    const float* __restrict__ scorer,
                                                    double* __restrict__ scores) {
    const int lane = threadIdx.x & 63;
    const int wave = threadIdx.x >> 6;

    // scorer fragment (same for every row)
    float4 sc = ((const float4*)scorer)[lane];

    // ||scorer|| in double (wave reduction; identical in every wave)
    double n2 = (double)sc.x * sc.x + (double)sc.y * sc.y +
                (double)sc.z * sc.z + (double)sc.w * sc.w;
    #pragma unroll
    for (int off = 32; off; off >>= 1) n2 += __shfl_xor(n2, off, 64);
    const double inv_norm = 1.0 / sqrt(n2);

    const long rows = (long)BB * NN;
    const long wid  = (long)blockIdx.x * 4 + wave;
    const long nw   = (long)gridDim.x * 4;

    for (long r = wid; r < rows; r += nw) {
        float4 v = ((const float4*)emb)[r * 64 + lane];
        double d = (double)v.x * sc.x + (double)v.y * sc.y +
                   (double)v.z * sc.z + (double)v.w * sc.w;
        #pragma unroll
        for (int off = 32; off; off >>= 1) d += __shfl_xor(d, off, 64);
        if (lane == 0) scores[r] = d * inv_norm + (double)mask[r];
    }
}

// ---------- phase 2: per-batch exact top-K (desc value, ties -> asc index) ----------
// One 1024-thread block per batch. 2x 11-bit radix passes on the top key bits to
// find a 22-bit prefix whose >=-set is a small superset of top-K, then bitonic
// sort of <=4096 candidates in LDS.
__global__ __launch_bounds__(1024) void select_kernel(const double* __restrict__ scores,
                                                      int* __restrict__ topk_idx,
                                                      float* __restrict__ gate) {
    const int b   = blockIdx.x;
    const int tid = threadIdx.x;
    const double* sc = scores + (long)b * NN;

    __shared__ unsigned int hist[2048];
    __shared__ unsigned long long prefix_sh;
    __shared__ int need_sh;
    __shared__ unsigned int cand_count;
    __shared__ unsigned long long keyA[4096];
    __shared__ int idxA[4096];

    if (tid == 0) { prefix_sh = 0ull; need_sh = KK; cand_count = 0u; }
    __syncthreads();

    const int shifts[2] = {53, 42};

    for (int p = 0; p < 2; p++) {
        for (int i = tid; i < 2048; i += 1024) hist[i] = 0u;
        __syncthreads();
        const unsigned long long pref = prefix_sh;
        const int sh = shifts[p];
        for (int i = tid * 2; i < NN; i += 2048) {
            double2 v = *(const double2*)(sc + i);
            unsigned long long k0 = key64(v.x);
            unsigned long long k1 = key64(v.y);
            if (p == 0 || (k0 >> 53) == pref) atomicAdd(&hist[(unsigned)((k0 >> sh) & 2047ull)], 1u);
            if (p == 0 || (k1 >> 53) == pref) atomicAdd(&hist[(unsigned)((k1 >> sh) & 2047ull)], 1u);
        }
        __syncthreads();
        if (tid == 0) {
            unsigned int cum = 0; int need = need_sh; int selbin = 0; unsigned int above = 0;
            for (int bin = 2047; bin >= 0; bin--) {
                unsigned int c = hist[bin];
                if (cum + c >= (unsigned int)need) { selbin = bin; above = cum; break; }
                cum += c;
            }
            prefix_sh = (prefix_sh << 11) | (unsigned long long)selbin;
            need_sh = need - (int)above;
        }
        __syncthreads();
    }

    // collect all elements with 22-bit prefix >= threshold prefix (superset of top-K)
    const unsigned long long pfx = prefix_sh;
    for (int i = tid * 2; i < NN; i += 2048) {
        double2 v = *(const double2*)(sc + i);
        unsigned long long k0 = key64(v.x);
        unsigned long long k1 = key64(v.y);
        if ((k0 >> 42) >= pfx) {
            unsigned int pos = atomicAdd(&cand_count, 1u);
            if (pos < 4096u) { keyA[pos] = k0; idxA[pos] = i; }
        }
        if ((k1 >> 42) >= pfx) {
            unsigned int pos = atomicAdd(&cand_count, 1u);
            if (pos < 4096u) { keyA[pos] = k1; idxA[pos] = i + 1; }
        }
    }
    __syncthreads();
    const unsigned int M = cand_count < 4096u ? cand_count : 4096u;
    for (int i = (int)M + tid; i < 4096; i += 1024) { keyA[i] = 0ull; idxA[i] = 0x7fffffff; }
    __syncthreads();

    // bitonic sort, 4096 elements: key descending, index ascending on key tie
    for (int kk = 2; kk <= 4096; kk <<= 1) {
        for (int j = kk >> 1; j > 0; j >>= 1) {
            for (int i = tid; i < 4096; i += 1024) {
                int partner = i ^ j;
                if (partner > i) {
                    unsigned long long ka = keyA[i], kb = keyA[partner];
                    int ia = idxA[i], ib = idxA[partner];
                    // precedes(a,b): a strictly before b in final (desc) order
                    bool a_before_b = (ka > kb) || (ka == kb && ia < ib);
                    bool b_before_a = (kb > ka) || (kb == ka && ib < ia);
                    bool descBlock = ((i & kk) == 0);
                    bool doSwap = descBlock ? b_before_a : a_before_b;
                    if (doSwap) {
                        keyA[i] = kb; keyA[partner] = ka;
                        idxA[i] = ib; idxA[partner] = ia;
                    }
                }
            }
            __syncthreads();
        }
    }

    for (int i = tid; i < KK; i += 1024) {
        int idx = idxA[i];
        topk_idx[b * KK + i] = idx;
        gate[b * KK + i] = tanhf((float)sc[idx]);
    }
}

// ---------- phase 3: out[b,f,k] = emb[b, idx[b,k], f] * gate[b,k] ----------
// 32 k-columns per block; LDS transpose for coalesced writes.
__global__ __launch_bounds__(256) void gather_kernel(const float* __restrict__ emb,
                                                     const int* __restrict__ topk_idx,
                                                     const float* __restrict__ gate,
                                                     float* __restrict__ out) {
    const int b  = blockIdx.x >> 5;   // 32 tiles per batch
    const int kt = blockIdx.x & 31;
    const int k0 = kt * 32;
    const int tid = threadIdx.x;

    __shared__ float tile[32][FF + 4];
    __shared__ int   s_idx[32];
    __shared__ float s_gate[32];

    if (tid < 32) {
        s_idx[tid]  = topk_idx[b * KK + k0 + tid];
        s_gate[tid] = gate[b * KK + k0 + tid];
    }
    __syncthreads();

    const int g = tid >> 6, lane = tid & 63;
    #pragma unroll
    for (int i = 0; i < 8; i++) {
        int kl = i * 4 + g;
        int row = s_idx[kl];
        float gt = s_gate[kl];
        float4 v = ((const float4*)(emb + ((long)b * NN + row) * FF))[lane];
        float* t = &tile[kl][lane * 4];
        t[0] = v.x * gt; t[1] = v.y * gt; t[2] = v.z * gt; t[3] = v.w * gt;
    }
    __syncthreads();

    const long outbase = ((long)b * FF) * KK + k0;
    #pragma unroll
    for (int c = 0; c < 32; c++) {
        int linear = c * 256 + tid;
        int f = linear >> 5;
        int k = linear & 31;
        out[outbase + (long)f * KK + k] = tile[k][f];
    }
}

extern "C" void kernel_launch(void* const* d_in, const int* in_sizes, int n_in,
                              void* d_out, int out_size, void* d_ws, size_t ws_size,
                              hipStream_t stream) {
    const float* emb    = (const float*)d_in[0];  // [B, N, F] fp32
    const float* mask   = (const float*)d_in[1];  // [B, N] fp32
    const float* scorer = (const float*)d_in[2];  // [F, 1] fp32
    float* out = (float*)d_out;                   // [B, F, K] fp32

    char* wsb = (char*)d_ws;
    double* scores  = (double*)wsb;                                   // B*N doubles = 3.2 MB
    int*    topkidx = (int*)(wsb + sizeof(double) * BB * NN);         // B*K ints
    float*  gate    = (float*)(wsb + sizeof(double) * BB * NN
                                   + sizeof(int) * BB * KK);          // B*K floats

    score_kernel<<<2048, 256, 0, stream>>>(emb, mask, scorer, scores);
    select_kernel<<<BB, 1024, 0, stream>>>(scores, topkidx, gate);
    gather_kernel<<<BB * 32, 256, 0, stream>>>(emb, topkidx, gate, out);
}

// Round 2
// 719.672 us; speedup vs baseline: 1.0497x; 1.0497x over previous
//
#include <hip/hip_runtime.h>
#include <math.h>

#define BB 8
#define NN 50000
#define FF 256
#define KK 1024
#define CHUNK 400
#define NCHUNK 125   // 125 * 400 = 50000 exactly

// ---------- helpers ----------
__device__ __forceinline__ unsigned long long key64(double x) {
    unsigned long long u = (unsigned long long)__double_as_longlong(x);
    // monotone map: negative -> flip all bits, positive -> flip sign bit
    u ^= (u & 0x8000000000000000ull) ? 0xFFFFFFFFFFFFFFFFull : 0x8000000000000000ull;
    return u;
}
__device__ __forceinline__ double key_to_double(unsigned long long k) {
    unsigned long long u = (k & 0x8000000000000000ull) ? (k ^ 0x8000000000000000ull) : ~k;
    return __longlong_as_double((long long)u);
}

// ---------- zero the global histogram (ws is poisoned 0xAA) ----------
__global__ __launch_bounds__(1024) void zero_kernel(unsigned int* __restrict__ p, int n) {
    int i = blockIdx.x * 1024 + threadIdx.x;
    if (i < n) p[i] = 0u;
}

// ---------- phase 1: scores + fused 11-bit radix histogram ----------
// One block per (batch, 400-row chunk); wave-per-row, 4 rows in flight per wave
// so the 6-step double shuffle chains overlap.
__global__ __launch_bounds__(256) void score_kernel(const float* __restrict__ emb,
                                                    const float* __restrict__ mask,
                                                    const float* __restrict__ scorer,
                                                    double* __restrict__ scores,
                                                    unsigned int* __restrict__ ghist) {
    const int b    = blockIdx.x / NCHUNK;
    const int c    = blockIdx.x % NCHUNK;
    const int n0   = c * CHUNK;
    const int lane = threadIdx.x & 63;
    const int wave = threadIdx.x >> 6;

    __shared__ unsigned int h[2048];
    __shared__ float smask[CHUNK];
    for (int i = threadIdx.x; i < 2048; i += 256) h[i] = 0u;
    for (int i = threadIdx.x; i < CHUNK; i += 256) smask[i] = mask[b * NN + n0 + i];
    __syncthreads();

    float4 sc = ((const float4*)scorer)[lane];
    double n2 = (double)sc.x * sc.x + (double)sc.y * sc.y +
                (double)sc.z * sc.z + (double)sc.w * sc.w;
    #pragma unroll
    for (int off = 32; off; off >>= 1) n2 += __shfl_xor(n2, off, 64);
    const double inv_norm = 1.0 / sqrt(n2);

    const float* base  = emb + ((long)b * NN + n0) * FF;
    double*      sbase = scores + (long)b * NN + n0;

    for (int it = 0; it < CHUNK / 16; ++it) {   // 25 iterations
        const int nn = it * 16 + wave * 4;      // 4 consecutive rows per wave
        double d[4];
        #pragma unroll
        for (int j = 0; j < 4; j++) {
            float4 v = ((const float4*)(base + (nn + j) * FF))[lane];
            d[j] = (double)v.x * sc.x + (double)v.y * sc.y +
                   (double)v.z * sc.z + (double)v.w * sc.w;
        }
        #pragma unroll
        for (int off = 32; off; off >>= 1) {
            #pragma unroll
            for (int j = 0; j < 4; j++) d[j] += __shfl_xor(d[j], off, 64);
        }
        if (lane == 0) {
            double s[4];
            #pragma unroll
            for (int j = 0; j < 4; j++) {
                s[j] = d[j] * inv_norm + (double)smask[nn + j];
                atomicAdd(&h[(unsigned)(key64(s[j]) >> 53)], 1u);
            }
            *(double2*)(sbase + nn)     = make_double2(s[0], s[1]);
            *(double2*)(sbase + nn + 2) = make_double2(s[2], s[3]);
        }
    }
    __syncthreads();

    unsigned int* gh = ghist + b * 2048;
    for (int i = threadIdx.x; i < 2048; i += 256) {
        unsigned int v = h[i];
        if (v) atomicAdd(&gh[i], v);
    }
}

// ---------- phase 2: per-batch exact top-K (desc value, ties -> asc index) ----------
// One 1024-thread block per batch. Starts from precomputed hist1; one in-LDS
// suffix scan picks bin1; one score scan builds hist2 (bits 52..42) restricted
// to bin1; a second suffix scan picks bin2; one scan collects the <=4096
// candidate superset; O(M^2) rank (LDS broadcast, no barriers) emits order.
__global__ __launch_bounds__(1024) void select_kernel(const double* __restrict__ scores,
                                                      const unsigned int* __restrict__ ghist,
                                                      int* __restrict__ topk_idx,
                                                      float* __restrict__ gate) {
    const int b   = blockIdx.x;
    const int tid = threadIdx.x;
    const double* sc = scores + (long)b * NN;

    __shared__ unsigned int h[2048];
    __shared__ unsigned long long keyA[4096];
    __shared__ int idxA[4096];
    __shared__ int bin1_s, need2_s, bin2_s;
    __shared__ unsigned int cnt;

    const int i0 = tid, i1 = tid + 1024;

    h[i0] = ghist[b * 2048 + i0];
    h[i1] = ghist[b * 2048 + i1];
    if (tid == 0) cnt = 0u;
    __syncthreads();

    // suffix scan #1
    for (int off = 1; off < 2048; off <<= 1) {
        unsigned a0 = (i0 + off < 2048) ? h[i0 + off] : 0u;
        unsigned a1 = (i1 + off < 2048) ? h[i1 + off] : 0u;
        __syncthreads();
        h[i0] += a0; h[i1] += a1;
        __syncthreads();
    }
    if (h[i0] >= (unsigned)KK && (i0 == 2047 || h[i0 + 1] < (unsigned)KK)) {
        bin1_s = i0; need2_s = KK - (int)((i0 == 2047) ? 0u : h[i0 + 1]);
    }
    if (h[i1] >= (unsigned)KK && (i1 == 2047 || h[i1 + 1] < (unsigned)KK)) {
        bin1_s = i1; need2_s = KK - (int)((i1 == 2047) ? 0u : h[i1 + 1]);
    }
    __syncthreads();
    const unsigned long long bin1 = (unsigned long long)bin1_s;
    const unsigned need2 = (unsigned)need2_s;

    // hist2 over bits 52..42, restricted to bin1
    h[i0] = 0u; h[i1] = 0u;
    __syncthreads();
    for (int i = tid; i < NN / 2; i += 1024) {
        double2 v = ((const double2*)sc)[i];
        unsigned long long k0 = key64(v.x), k1 = key64(v.y);
        if ((k0 >> 53) == bin1) atomicAdd(&h[(unsigned)((k0 >> 42) & 2047ull)], 1u);
        if ((k1 >> 53) == bin1) atomicAdd(&h[(unsigned)((k1 >> 42) & 2047ull)], 1u);
    }
    __syncthreads();

    // suffix scan #2
    for (int off = 1; off < 2048; off <<= 1) {
        unsigned a0 = (i0 + off < 2048) ? h[i0 + off] : 0u;
        unsigned a1 = (i1 + off < 2048) ? h[i1 + off] : 0u;
        __syncthreads();
        h[i0] += a0; h[i1] += a1;
        __syncthreads();
    }
    if (h[i0] >= need2 && (i0 == 2047 || h[i0 + 1] < need2)) bin2_s = i0;
    if (h[i1] >= need2 && (i1 == 2047 || h[i1 + 1] < need2)) bin2_s = i1;
    __syncthreads();
    const unsigned long long pfx = (bin1 << 11) | (unsigned long long)bin2_s;

    // collect candidate superset (22-bit prefix >= pfx)
    for (int i = tid; i < NN / 2; i += 1024) {
        double2 v = ((const double2*)sc)[i];
        unsigned long long k0 = key64(v.x), k1 = key64(v.y);
        if ((k0 >> 42) >= pfx) {
            unsigned p = atomicAdd(&cnt, 1u);
            if (p < 4096u) { keyA[p] = k0; idxA[p] = 2 * i; }
        }
        if ((k1 >> 42) >= pfx) {
            unsigned p = atomicAdd(&cnt, 1u);
            if (p < 4096u) { keyA[p] = k1; idxA[p] = 2 * i + 1; }
        }
    }
    __syncthreads();
    const int M = (int)(cnt < 4096u ? cnt : 4096u);

    // O(M^2) rank: rank(i) = #{j: key_j > key_i or (key_j == key_i and idx_j < idx_i)}
    for (int i = tid; i < M; i += 1024) {
        const unsigned long long ki = keyA[i];
        const int ii = idxA[i];
        int rank = 0;
        for (int j = 0; j < M; ++j) {
            const unsigned long long kj = keyA[j];
            rank += (kj > ki) || (kj == ki && idxA[j] < ii);
        }
        if (rank < KK) {
            topk_idx[b * KK + rank] = ii;
            gate[b * KK + rank]     = tanhf((float)key_to_double(ki));
        }
    }
}

// ---------- phase 3: out[b,f,k] = emb[b, idx[b,k], f] * gate[b,k] ----------
__global__ __launch_bounds__(256) void gather_kernel(const float* __restrict__ emb,
                                                     const int* __restrict__ topk_idx,
                                                     const float* __restrict__ gate,
                                                     float* __restrict__ out) {
    const int b  = blockIdx.x >> 5;
    const int kt = blockIdx.x & 31;
    const int k0 = kt * 32;
    const int tid = threadIdx.x;

    __shared__ float tile[32][FF + 4];
    __shared__ int   s_idx[32];
    __shared__ float s_gate[32];

    if (tid < 32) {
        s_idx[tid]  = topk_idx[b * KK + k0 + tid];
        s_gate[tid] = gate[b * KK + k0 + tid];
    }
    __syncthreads();

    const int g = tid >> 6, lane = tid & 63;
    #pragma unroll
    for (int i = 0; i < 8; i++) {
        int kl = i * 4 + g;
        int row = s_idx[kl];
        float gt = s_gate[kl];
        float4 v = ((const float4*)(emb + ((long)b * NN + row) * FF))[lane];
        float* t = &tile[kl][lane * 4];
        t[0] = v.x * gt; t[1] = v.y * gt; t[2] = v.z * gt; t[3] = v.w * gt;
    }
    __syncthreads();

    const long outbase = ((long)b * FF) * KK + k0;
    #pragma unroll
    for (int c = 0; c < 32; c++) {
        int linear = c * 256 + tid;
        int f = linear >> 5;
        int k = linear & 31;
        out[outbase + (long)f * KK + k] = tile[k][f];
    }
}

extern "C" void kernel_launch(void* const* d_in, const int* in_sizes, int n_in,
                              void* d_out, int out_size, void* d_ws, size_t ws_size,
                              hipStream_t stream) {
    const float* emb    = (const float*)d_in[0];  // [B, N, F] fp32
    const float* mask   = (const float*)d_in[1];  // [B, N] fp32
    const float* scorer = (const float*)d_in[2];  // [F, 1] fp32
    float* out = (float*)d_out;                   // [B, F, K] fp32

    char* wsb = (char*)d_ws;
    double*       scores  = (double*)wsb;                               // B*N doubles = 3.2 MB
    unsigned int* ghist   = (unsigned int*)(wsb + sizeof(double) * BB * NN);
    int*          topkidx = (int*)((char*)ghist + sizeof(unsigned int) * BB * 2048);
    float*        gatep   = (float*)((char*)topkidx + sizeof(int) * BB * KK);

    zero_kernel<<<16, 1024, 0, stream>>>(ghist, BB * 2048);
    score_kernel<<<BB * NCHUNK, 256, 0, stream>>>(emb, mask, scorer, scores, ghist);
    select_kernel<<<BB, 1024, 0, stream>>>(scores, ghist, topkidx, gatep);
    gather_kernel<<<BB * 32, 256, 0, stream>>>(emb, topkidx, gatep, out);
}